// Round 15
// baseline (95.363 us; speedup 1.0000x reference)
//
#include <hip/hip_runtime.h>

// MLPScorer: out[b,t,s] = sum_d v[d] * tanh( (h_t Wq^T + bq)[b,t,d] + (h_s Wc^T)[b,s,d] )
// B=4, T=S=D=512, all f32.
//
// tanh(x) = 1 - 2/(1+e^{2x});  e^{2(a+u)} = ea*eu (separable; precomputed in the
// GEMM epilogue as exp2(c*...), c = 2*log2(e)).
// Scorer: two 4-term rational chains in lo/hi of packed f32; 1 rcp per 4 terms.
// Uniform A/v via constant-AS s_load ping-pong (r10 internals).
//
// THIS ROUND: the untested grid cell — wave = 4t x 64s (ONE s-col/lane,
// 0.5 B/update U-traffic) AND 4 waves/SIMD (grid 2048 x 128thr = 4096 waves).
// r10 = same internals @2 waves/SIMD; r13 = 4 waves/SIMD but 2t (2x traffic).
// GEMM: round-12 verbatim (MFMA bf16, ~8us, passing).

#define B_ 4
#define T_ 512
#define S_ 512
#define D_ 512

typedef float v2f __attribute__((ext_vector_type(2)));
typedef __attribute__((address_space(4))) const float kfloat;  // constant AS -> s_load
typedef __attribute__((ext_vector_type(8))) short bf16x8;      // 8 bf16 (4 VGPRs)
typedef __attribute__((ext_vector_type(4))) float f32x4;

static constexpr float C2LOG2E = 2.8853900817779268f; // 2*log2(e)

__device__ __forceinline__ v2f pkfma(v2f a, v2f b, v2f c) {
    return __builtin_elementwise_fma(a, b, c);
}

// ---------------------------------------------------------------------------
// Dual GEMM (MFMA bf16) + exp2 epilogue, both jobs Out = X * W^T (K = 512):
//  job0: X=h_t [2048][512], W=Wq  [512][512] -> Ea [2048][512] (+bq), natural
//  job1: X=Wc  [512][512],  W=h_s [2048][512] -> Eu4, d-quad-major:
//        Eu4[ ((d>>2)*2048 + col)*4 + (d&3) ], col = b*S+s
// ---------------------------------------------------------------------------
#define LDK 64        // k-chunk
#define LSTR 72       // LDS row stride in bf16 elems (144B = 9 x 16B)

__global__ __launch_bounds__(256) void gemm_exp_kernel(
    const float* __restrict__ Ht, const float* __restrict__ Hs,
    const float* __restrict__ Wq, const float* __restrict__ bq,
    const float* __restrict__ Wc,
    float* __restrict__ Ea, float* __restrict__ Eu4)
{
    __shared__ __bf16 Xb[64 * LSTR];   // [row][k] bf16
    __shared__ __bf16 Wb[64 * LSTR];   // [col][k] bf16

    const int job = blockIdx.z;
    const float* __restrict__ X = job ? Wc : Ht;
    const float* __restrict__ W = job ? Hs : Wq;
    const int r0 = (job ? blockIdx.y : blockIdx.x) * 64;   // X-row block
    const int e0 = (job ? blockIdx.x : blockIdx.y) * 64;   // W-row (out col) block

    const int tid  = threadIdx.x;
    const int lane = tid & 63;
    const int wv   = tid >> 6;         // wave 0..3 -> m-rows 16*wv..16*wv+15
    const int srow = tid >> 2;         // staging row 0..63
    const int skq  = (tid & 3) << 4;   // staging k offset: 0,16,32,48 floats

    f32x4 acc[4] = {{0.f,0.f,0.f,0.f},{0.f,0.f,0.f,0.f},
                    {0.f,0.f,0.f,0.f},{0.f,0.f,0.f,0.f}};

    const float* Xrow = X + (size_t)(r0 + srow) * D_ + skq;
    const float* Wrow = W + (size_t)(e0 + srow) * D_ + skq;

    // prefetch chunk 0
    float4 xr0 = *(const float4*)(Xrow + 0), xr1 = *(const float4*)(Xrow + 4);
    float4 xr2 = *(const float4*)(Xrow + 8), xr3 = *(const float4*)(Xrow + 12);
    float4 wr0 = *(const float4*)(Wrow + 0), wr1 = *(const float4*)(Wrow + 4);
    float4 wr2 = *(const float4*)(Wrow + 8), wr3 = *(const float4*)(Wrow + 12);

    for (int k0 = 0; k0 < D_; k0 += LDK) {
        __syncthreads();   // previous chunk's LDS reads done
        {
            union { __bf16 h[16]; uint4 q[2]; } ux, uw;
#pragma unroll
            for (int j = 0; j < 4; ++j) {
                ux.h[j+ 0] = (__bf16)(&xr0.x)[j];  uw.h[j+ 0] = (__bf16)(&wr0.x)[j];
                ux.h[j+ 4] = (__bf16)(&xr1.x)[j];  uw.h[j+ 4] = (__bf16)(&wr1.x)[j];
                ux.h[j+ 8] = (__bf16)(&xr2.x)[j];  uw.h[j+ 8] = (__bf16)(&wr2.x)[j];
                ux.h[j+12] = (__bf16)(&xr3.x)[j];  uw.h[j+12] = (__bf16)(&wr3.x)[j];
            }
            *(uint4*)&Xb[srow * LSTR + skq]     = ux.q[0];
            *(uint4*)&Xb[srow * LSTR + skq + 8] = ux.q[1];
            *(uint4*)&Wb[srow * LSTR + skq]     = uw.q[0];
            *(uint4*)&Wb[srow * LSTR + skq + 8] = uw.q[1];
        }
        __syncthreads();
        if (k0 + LDK < D_) {   // issue next chunk's loads; land during MFMAs
            xr0 = *(const float4*)(Xrow + k0 + LDK + 0);
            xr1 = *(const float4*)(Xrow + k0 + LDK + 4);
            xr2 = *(const float4*)(Xrow + k0 + LDK + 8);
            xr3 = *(const float4*)(Xrow + k0 + LDK + 12);
            wr0 = *(const float4*)(Wrow + k0 + LDK + 0);
            wr1 = *(const float4*)(Wrow + k0 + LDK + 4);
            wr2 = *(const float4*)(Wrow + k0 + LDK + 8);
            wr3 = *(const float4*)(Wrow + k0 + LDK + 12);
        }
#pragma unroll
        for (int kk = 0; kk < 2; ++kk) {
            const int ko = (kk << 5) + ((lane >> 4) << 3);   // k offset in chunk
            const bf16x8 af = *(const bf16x8*)&Xb[(16 * wv + (lane & 15)) * LSTR + ko];
#pragma unroll
            for (int c = 0; c < 4; ++c) {
                const bf16x8 bf = *(const bf16x8*)&Wb[(16 * c + (lane & 15)) * LSTR + ko];
                acc[c] = __builtin_amdgcn_mfma_f32_16x16x32_bf16(af, bf, acc[c], 0, 0, 0);
            }
        }
    }

    // epilogue: D[m][n] -> lane holds m = 16*wv + (lane>>4)*4 + j, n = 16*c + (lane&15)
    if (!job) {
        const int m0 = r0 + 16 * wv + ((lane >> 4) << 2);
#pragma unroll
        for (int c = 0; c < 4; ++c) {
            const int E = e0 + 16 * c + (lane & 15);
            const float bb = bq[E];
#pragma unroll
            for (int j = 0; j < 4; ++j) {
                Ea[(size_t)(m0 + j) * 512 + E] =
                    __builtin_amdgcn_exp2f(C2LOG2E * (acc[c][j] + bb));
            }
        }
    } else {
        // d-rows: R = r0+16wv+(lane>>4)*4+j -> R&3 = j, R>>2 = (r0+16wv)/4 + (lane>>4)
        const int R4 = ((r0 + 16 * wv) >> 2) + (lane >> 4);
#pragma unroll
        for (int c = 0; c < 4; ++c) {
            const int E = e0 + 16 * c + (lane & 15);
            float4 o;   // j = d&3 varies inside the float4 -> consecutive addresses
            o.x = __builtin_amdgcn_exp2f(C2LOG2E * acc[c][0]);
            o.y = __builtin_amdgcn_exp2f(C2LOG2E * acc[c][1]);
            o.z = __builtin_amdgcn_exp2f(C2LOG2E * acc[c][2]);
            o.w = __builtin_amdgcn_exp2f(C2LOG2E * acc[c][3]);
            *(float4*)(Eu4 + ((size_t)R4 * 2048 + E) * 4) = o;
        }
    }
}

// ---------------------------------------------------------------------------
// Scorer. Block = 2 waves (128 thr); block tile 4t x 128s.
// Wave: 4t x 64s -> each lane owns ONE s column (min U traffic, 0.5 B/update).
// Uniform A/v: constant-AS s_loads, ping-pong double-buffered (r10 internals).
// Per-lane Eu4: one coalesced dwordx4 stream, distance-1 prefetch.
// Grid 2048 = 4096 waves = 4 waves/SIMD. XCD decode id%8 = (b, s-half).
// ---------------------------------------------------------------------------
__global__ __launch_bounds__(128, 4) void score_kernel(
    const float* __restrict__ Ea,   // [B*T][512]
    const float* __restrict__ Eu4,  // [(512/4)][2048][4]
    const float* __restrict__ v, float* __restrict__ out)
{
    const int tid  = threadIdx.x;   // 0..127
    const int lane = tid & 63;
    const int w    = tid >> 6;      // 0..1
    const int id   = blockIdx.x;
    const int gg   = id & 7;        // XCD group: (b, s-half)
    const int b    = gg >> 1;
    const int shlf = gg & 1;
    const int k    = id >> 3;       // 0..255
    const int sq   = k & 1;         // s-quarter within half
    const int tblk = k >> 1;        // 0..127
    const int t0   = tblk << 2;     // 4 t-rows per block
    const int s    = (shlf << 8) + (sq << 7) + (w << 6) + lane;

    // sumv = sum_d v[d], butterfly (all lanes get it)
    float p = 0.f;
#pragma unroll
    for (int q = 0; q < 8; ++q) p += v[lane + (q << 6)];
#pragma unroll
    for (int off = 32; off; off >>= 1) p += __shfl_xor(p, off);
    const float sumv = p;

    kfloat* Ac = (kfloat*)(unsigned long long)(Ea + (size_t)(b * T_ + t0) * D_);
    kfloat* vc = (kfloat*)(unsigned long long)v;
    const float* __restrict__ U = Eu4 + ((size_t)b * S_ + s) * 4;  // quad stride 8192

    v2f one; one.x = 1.0f; one.y = 1.0f;
    v2f acc0 = {}, acc1 = {}, acc2 = {}, acc3 = {};

    v2f pa[2][4][4];   // [buf][t-row][d-pair] uniform A (SGPR-resident)
    v2f pv[2][4];      // [buf][d-pair]        uniform v

#define LOAD_ROW(BUF, R, D0)                                            \
    pa[BUF][R][0] = (v2f){Ac[(R)*D_ + (D0) + 0], Ac[(R)*D_ + (D0) + 1]};\
    pa[BUF][R][1] = (v2f){Ac[(R)*D_ + (D0) + 2], Ac[(R)*D_ + (D0) + 3]};\
    pa[BUF][R][2] = (v2f){Ac[(R)*D_ + (D0) + 4], Ac[(R)*D_ + (D0) + 5]};\
    pa[BUF][R][3] = (v2f){Ac[(R)*D_ + (D0) + 6], Ac[(R)*D_ + (D0) + 7]};

#define LOAD_UNI(BUF, DG) {                                             \
    const int _d0 = (DG) << 3;                                          \
    pv[BUF][0] = (v2f){vc[_d0 + 0], vc[_d0 + 1]};                       \
    pv[BUF][1] = (v2f){vc[_d0 + 2], vc[_d0 + 3]};                       \
    pv[BUF][2] = (v2f){vc[_d0 + 4], vc[_d0 + 5]};                       \
    pv[BUF][3] = (v2f){vc[_d0 + 6], vc[_d0 + 7]};                       \
    LOAD_ROW(BUF, 0, _d0) LOAD_ROW(BUF, 1, _d0)                         \
    LOAD_ROW(BUF, 2, _d0) LOAD_ROW(BUF, 3, _d0) }

#define GRP8(BUF, R, u0, u1, u2, u3, ACC) {                             \
    const v2f F0 = pkfma(pa[BUF][R][0], u0, one);                       \
    const v2f F1 = pkfma(pa[BUF][R][1], u1, one);                       \
    const v2f F2 = pkfma(pa[BUF][R][2], u2, one);                       \
    const v2f F3 = pkfma(pa[BUF][R][3], u3, one);                       \
    const v2f g   = F0 * F1;                                            \
    const v2f h   = F2 * F3;                                            \
    const v2f n01 = pkfma(pv[BUF][1], F0, pv[BUF][0] * F1);             \
    const v2f n23 = pkfma(pv[BUF][3], F2, pv[BUF][2] * F3);             \
    const v2f num = pkfma(n23, g, n01 * h);                             \
    const v2f den = g * h;                                              \
    v2f r;                                                              \
    r.x = __builtin_amdgcn_rcpf(den.x);                                 \
    r.y = __builtin_amdgcn_rcpf(den.y);                                 \
    ACC = pkfma(num, r, ACC); }

#define COMPUTE(BUF, UQ0, UQ1) {                                        \
    const v2f u0 = {UQ0.x, UQ0.y}, u1 = {UQ0.z, UQ0.w};                 \
    const v2f u2 = {UQ1.x, UQ1.y}, u3 = {UQ1.z, UQ1.w};                 \
    GRP8(BUF, 0, u0, u1, u2, u3, acc0)                                  \
    GRP8(BUF, 1, u0, u1, u2, u3, acc1)                                  \
    GRP8(BUF, 2, u0, u1, u2, u3, acc2)                                  \
    GRP8(BUF, 3, u0, u1, u2, u3, acc3) }

#define LDQ(P, Q) (*(const float4*)((P) + (size_t)(Q) * 8192))

    // prologue: dg=0 current (buf0 + c-regs)
    float4 c0 = LDQ(U, 0), c1 = LDQ(U, 1);
    LOAD_UNI(0, 0)

    for (int dg = 0; dg < 62; dg += 2) {
        // prefetch dg+1 into buf1/n-regs
        const float4 n0 = LDQ(U, 2*dg + 2), n1 = LDQ(U, 2*dg + 3);
        LOAD_UNI(1, dg + 1)
        COMPUTE(0, c0, c1)
        // prefetch dg+2 into buf0/c-regs
        c0 = LDQ(U, 2*dg + 4); c1 = LDQ(U, 2*dg + 5);
        LOAD_UNI(0, dg + 2)
        COMPUTE(1, n0, n1)
    }
    // epilogue: dg=62 in buf0/c-regs; load dg=63
    {
        const float4 n0 = LDQ(U, 126), n1 = LDQ(U, 127);
        LOAD_UNI(1, 63)
        COMPUTE(0, c0, c1)
        COMPUTE(1, n0, n1)
    }
#undef LDQ
#undef COMPUTE
#undef GRP8
#undef LOAD_UNI
#undef LOAD_ROW

    float* __restrict__ O = out + (size_t)(b * T_ + t0) * S_ + s;
    O[0 * S_] = sumv - 2.0f * (acc0.x + acc0.y);
    O[1 * S_] = sumv - 2.0f * (acc1.x + acc1.y);
    O[2 * S_] = sumv - 2.0f * (acc2.x + acc2.y);
    O[3 * S_] = sumv - 2.0f * (acc3.x + acc3.y);
}

extern "C" void kernel_launch(void* const* d_in, const int* in_sizes, int n_in,
                              void* d_out, int out_size, void* d_ws, size_t ws_size,
                              hipStream_t stream) {
    const float* h_t = (const float*)d_in[0];  // [4,512,512]
    const float* h_s = (const float*)d_in[1];  // [4,512,512]
    const float* Wq  = (const float*)d_in[2];  // [512,512]
    const float* bq  = (const float*)d_in[3];  // [512]
    const float* Wc  = (const float*)d_in[4];  // [512,512]
    const float* v   = (const float*)d_in[5];  // [512]
    float* out = (float*)d_out;                // [4,512,512]

    float* Ea  = (float*)d_ws;                 // exp2(c*(h_t Wq^T + bq)) [2048][512]
    float* Eu4 = Ea + (size_t)B_ * T_ * D_;    // exp2(c*(h_s Wc^T)), d-quad-major

    gemm_exp_kernel<<<dim3(32, 8, 2), 256, 0, stream>>>(h_t, h_s, Wq, bq, Wc, Ea, Eu4);
    score_kernel<<<dim3(2048, 1, 1), 128, 0, stream>>>(Ea, Eu4, v, out);
}

// Round 16
// 62.156 us; speedup vs baseline: 1.5342x; 1.5342x over previous
//
#include <hip/hip_runtime.h>

// MLPScorer: out[b,t,s] = sum_d v[d] * tanh( (h_t Wq^T + bq)[b,t,d] + (h_s Wc^T)[b,s,d] )
// B=4, T=S=D=512, all f32.
//
// FINAL CONFIG (= round-12, best measured 63.0 us):
//  - tanh(x) = 1 - 2/(1+e^{2x});  e^{2(a+u)} = ea*eu (separable) -> GEMM epilogue
//    writes Ea = exp2(c*(h_t Wq^T + bq)), Eu4 = exp2(c*(h_s Wc^T)) transposed
//    d-quad-major; c = 2*log2(e).
//  - GEMM: MFMA bf16 (mfma_f32_16x16x32_bf16), 64x64 tile, K-chunk 64 in LDS
//    (stride 72 elems), issue-early/write-late staging.  ~8 us.
//  - Scorer: two 4-term rational chains in lo/hi of packed f32 (1 rcp / 4 d);
//    uniform A/v via constant-AS s_load ping-pong; per-lane Eu4 coalesced
//    dwordx4 distance-1 prefetch; wave = 4t x 128s (2 s-cols/lane).  ~55 us
//    = 1.66x its f32-VALU issue floor (33 us busy, measured at the floor).

#define B_ 4
#define T_ 512
#define S_ 512
#define D_ 512

typedef float v2f __attribute__((ext_vector_type(2)));
typedef __attribute__((address_space(4))) const float kfloat;  // constant AS -> s_load
typedef __attribute__((ext_vector_type(8))) short bf16x8;      // 8 bf16 (4 VGPRs)
typedef __attribute__((ext_vector_type(4))) float f32x4;

static constexpr float C2LOG2E = 2.8853900817779268f; // 2*log2(e)

__device__ __forceinline__ v2f pkfma(v2f a, v2f b, v2f c) {
    return __builtin_elementwise_fma(a, b, c);
}

// ---------------------------------------------------------------------------
// Dual GEMM (MFMA bf16) + exp2 epilogue, both jobs Out = X * W^T (K = 512):
//  job0: X=h_t [2048][512], W=Wq  [512][512] -> Ea [2048][512] (+bq), natural
//  job1: X=Wc  [512][512],  W=h_s [2048][512] -> Eu4, d-quad-major:
//        Eu4[ ((d>>2)*2048 + col)*4 + (d&3) ], col = b*S+s
// ---------------------------------------------------------------------------
#define LDK 64        // k-chunk
#define LSTR 72       // LDS row stride in bf16 elems (144B = 9 x 16B)

__global__ __launch_bounds__(256) void gemm_exp_kernel(
    const float* __restrict__ Ht, const float* __restrict__ Hs,
    const float* __restrict__ Wq, const float* __restrict__ bq,
    const float* __restrict__ Wc,
    float* __restrict__ Ea, float* __restrict__ Eu4)
{
    __shared__ __bf16 Xb[64 * LSTR];   // [row][k] bf16
    __shared__ __bf16 Wb[64 * LSTR];   // [col][k] bf16

    const int job = blockIdx.z;
    const float* __restrict__ X = job ? Wc : Ht;
    const float* __restrict__ W = job ? Hs : Wq;
    const int r0 = (job ? blockIdx.y : blockIdx.x) * 64;   // X-row block
    const int e0 = (job ? blockIdx.x : blockIdx.y) * 64;   // W-row (out col) block

    const int tid  = threadIdx.x;
    const int lane = tid & 63;
    const int wv   = tid >> 6;         // wave 0..3 -> m-rows 16*wv..16*wv+15
    const int srow = tid >> 2;         // staging row 0..63
    const int skq  = (tid & 3) << 4;   // staging k offset: 0,16,32,48 floats

    f32x4 acc[4] = {{0.f,0.f,0.f,0.f},{0.f,0.f,0.f,0.f},
                    {0.f,0.f,0.f,0.f},{0.f,0.f,0.f,0.f}};

    const float* Xrow = X + (size_t)(r0 + srow) * D_ + skq;
    const float* Wrow = W + (size_t)(e0 + srow) * D_ + skq;

    // prefetch chunk 0
    float4 xr0 = *(const float4*)(Xrow + 0), xr1 = *(const float4*)(Xrow + 4);
    float4 xr2 = *(const float4*)(Xrow + 8), xr3 = *(const float4*)(Xrow + 12);
    float4 wr0 = *(const float4*)(Wrow + 0), wr1 = *(const float4*)(Wrow + 4);
    float4 wr2 = *(const float4*)(Wrow + 8), wr3 = *(const float4*)(Wrow + 12);

    for (int k0 = 0; k0 < D_; k0 += LDK) {
        __syncthreads();   // previous chunk's LDS reads done
        {
            union { __bf16 h[16]; uint4 q[2]; } ux, uw;
#pragma unroll
            for (int j = 0; j < 4; ++j) {
                ux.h[j+ 0] = (__bf16)(&xr0.x)[j];  uw.h[j+ 0] = (__bf16)(&wr0.x)[j];
                ux.h[j+ 4] = (__bf16)(&xr1.x)[j];  uw.h[j+ 4] = (__bf16)(&wr1.x)[j];
                ux.h[j+ 8] = (__bf16)(&xr2.x)[j];  uw.h[j+ 8] = (__bf16)(&wr2.x)[j];
                ux.h[j+12] = (__bf16)(&xr3.x)[j];  uw.h[j+12] = (__bf16)(&wr3.x)[j];
            }
            *(uint4*)&Xb[srow * LSTR + skq]     = ux.q[0];
            *(uint4*)&Xb[srow * LSTR + skq + 8] = ux.q[1];
            *(uint4*)&Wb[srow * LSTR + skq]     = uw.q[0];
            *(uint4*)&Wb[srow * LSTR + skq + 8] = uw.q[1];
        }
        __syncthreads();
        if (k0 + LDK < D_) {   // issue next chunk's loads; land during MFMAs
            xr0 = *(const float4*)(Xrow + k0 + LDK + 0);
            xr1 = *(const float4*)(Xrow + k0 + LDK + 4);
            xr2 = *(const float4*)(Xrow + k0 + LDK + 8);
            xr3 = *(const float4*)(Xrow + k0 + LDK + 12);
            wr0 = *(const float4*)(Wrow + k0 + LDK + 0);
            wr1 = *(const float4*)(Wrow + k0 + LDK + 4);
            wr2 = *(const float4*)(Wrow + k0 + LDK + 8);
            wr3 = *(const float4*)(Wrow + k0 + LDK + 12);
        }
#pragma unroll
        for (int kk = 0; kk < 2; ++kk) {
            const int ko = (kk << 5) + ((lane >> 4) << 3);   // k offset in chunk
            const bf16x8 af = *(const bf16x8*)&Xb[(16 * wv + (lane & 15)) * LSTR + ko];
#pragma unroll
            for (int c = 0; c < 4; ++c) {
                const bf16x8 bf = *(const bf16x8*)&Wb[(16 * c + (lane & 15)) * LSTR + ko];
                acc[c] = __builtin_amdgcn_mfma_f32_16x16x32_bf16(af, bf, acc[c], 0, 0, 0);
            }
        }
    }

    // epilogue: D[m][n] -> lane holds m = 16*wv + (lane>>4)*4 + j, n = 16*c + (lane&15)
    if (!job) {
        const int m0 = r0 + 16 * wv + ((lane >> 4) << 2);
#pragma unroll
        for (int c = 0; c < 4; ++c) {
            const int E = e0 + 16 * c + (lane & 15);
            const float bb = bq[E];
#pragma unroll
            for (int j = 0; j < 4; ++j) {
                Ea[(size_t)(m0 + j) * 512 + E] =
                    __builtin_amdgcn_exp2f(C2LOG2E * (acc[c][j] + bb));
            }
        }
    } else {
        // d-rows: R = r0+16wv+(lane>>4)*4+j -> R&3 = j, R>>2 = (r0+16wv)/4 + (lane>>4)
        const int R4 = ((r0 + 16 * wv) >> 2) + (lane >> 4);
#pragma unroll
        for (int c = 0; c < 4; ++c) {
            const int E = e0 + 16 * c + (lane & 15);
            float4 o;   // j = d&3 varies inside the float4 -> consecutive addresses
            o.x = __builtin_amdgcn_exp2f(C2LOG2E * acc[c][0]);
            o.y = __builtin_amdgcn_exp2f(C2LOG2E * acc[c][1]);
            o.z = __builtin_amdgcn_exp2f(C2LOG2E * acc[c][2]);
            o.w = __builtin_amdgcn_exp2f(C2LOG2E * acc[c][3]);
            *(float4*)(Eu4 + ((size_t)R4 * 2048 + E) * 4) = o;
        }
    }
}

// ---------------------------------------------------------------------------
// Scorer. Block = 2 waves (128 thr); block tile 4t x 256s.
// Wave: 4t x 128s -> each lane owns s0 and s0+64 (two accumulator sets).
// Uniform A/v: constant-AS s_loads, ping-pong double-buffered (pa/pv).
// Per-lane Eu4: coalesced dwordx4 streams, distance-1 prefetch.
// Grid 1024, XCD decode id%8 = (b, s-half).
// ---------------------------------------------------------------------------
__global__ __launch_bounds__(128, 2) void score_kernel(
    const float* __restrict__ Ea,   // [B*T][512]
    const float* __restrict__ Eu4,  // [(512/4)][2048][4]
    const float* __restrict__ v, float* __restrict__ out)
{
    const int tid  = threadIdx.x;   // 0..127
    const int lane = tid & 63;
    const int w    = tid >> 6;      // 0..1
    const int id   = blockIdx.x;
    const int gg   = id & 7;        // XCD group: (b, s-half)
    const int b    = gg >> 1;
    const int shlf = gg & 1;
    const int tblk = id >> 3;       // 0..127
    const int t0   = tblk << 2;     // 4 t-rows per block
    const int s0   = (shlf << 8) + (w << 7) + lane;   // second column = s0 + 64

    // sumv = sum_d v[d], butterfly (all lanes get it)
    float p = 0.f;
#pragma unroll
    for (int q = 0; q < 8; ++q) p += v[lane + (q << 6)];
#pragma unroll
    for (int off = 32; off; off >>= 1) p += __shfl_xor(p, off);
    const float sumv = p;

    kfloat* Ac = (kfloat*)(unsigned long long)(Ea + (size_t)(b * T_ + t0) * D_);
    kfloat* vc = (kfloat*)(unsigned long long)v;
    const float* __restrict__ U0 = Eu4 + ((size_t)b * S_ + s0) * 4;  // quad stride 8192
    const float* __restrict__ U1 = U0 + 256;                          // s0 + 64

    v2f one; one.x = 1.0f; one.y = 1.0f;
    v2f accA0 = {}, accA1 = {}, accA2 = {}, accA3 = {};
    v2f accB0 = {}, accB1 = {}, accB2 = {}, accB3 = {};

    v2f pa[2][4][4];   // [buf][t-row][d-pair] uniform A (SGPR-resident)
    v2f pv[2][4];      // [buf][d-pair]        uniform v

#define LOAD_ROW(BUF, R, D0)                                            \
    pa[BUF][R][0] = (v2f){Ac[(R)*D_ + (D0) + 0], Ac[(R)*D_ + (D0) + 1]};\
    pa[BUF][R][1] = (v2f){Ac[(R)*D_ + (D0) + 2], Ac[(R)*D_ + (D0) + 3]};\
    pa[BUF][R][2] = (v2f){Ac[(R)*D_ + (D0) + 4], Ac[(R)*D_ + (D0) + 5]};\
    pa[BUF][R][3] = (v2f){Ac[(R)*D_ + (D0) + 6], Ac[(R)*D_ + (D0) + 7]};

#define LOAD_UNI(BUF, DG) {                                             \
    const int _d0 = (DG) << 3;                                          \
    pv[BUF][0] = (v2f){vc[_d0 + 0], vc[_d0 + 1]};                       \
    pv[BUF][1] = (v2f){vc[_d0 + 2], vc[_d0 + 3]};                       \
    pv[BUF][2] = (v2f){vc[_d0 + 4], vc[_d0 + 5]};                       \
    pv[BUF][3] = (v2f){vc[_d0 + 6], vc[_d0 + 7]};                       \
    LOAD_ROW(BUF, 0, _d0) LOAD_ROW(BUF, 1, _d0)                         \
    LOAD_ROW(BUF, 2, _d0) LOAD_ROW(BUF, 3, _d0) }

#define GRP8(BUF, R, u0, u1, u2, u3, ACC) {                             \
    const v2f F0 = pkfma(pa[BUF][R][0], u0, one);                       \
    const v2f F1 = pkfma(pa[BUF][R][1], u1, one);                       \
    const v2f F2 = pkfma(pa[BUF][R][2], u2, one);                       \
    const v2f F3 = pkfma(pa[BUF][R][3], u3, one);                       \
    const v2f g   = F0 * F1;                                            \
    const v2f h   = F2 * F3;                                            \
    const v2f n01 = pkfma(pv[BUF][1], F0, pv[BUF][0] * F1);             \
    const v2f n23 = pkfma(pv[BUF][3], F2, pv[BUF][2] * F3);             \
    const v2f num = pkfma(n23, g, n01 * h);                             \
    const v2f den = g * h;                                              \
    v2f r;                                                              \
    r.x = __builtin_amdgcn_rcpf(den.x);                                 \
    r.y = __builtin_amdgcn_rcpf(den.y);                                 \
    ACC = pkfma(num, r, ACC); }

#define COMPUTE(BUF, UA0, UA1, UB0, UB1) {                              \
    const v2f ua0 = {UA0.x, UA0.y}, ua1 = {UA0.z, UA0.w};               \
    const v2f ua2 = {UA1.x, UA1.y}, ua3 = {UA1.z, UA1.w};               \
    GRP8(BUF, 0, ua0, ua1, ua2, ua3, accA0)                             \
    GRP8(BUF, 1, ua0, ua1, ua2, ua3, accA1)                             \
    GRP8(BUF, 2, ua0, ua1, ua2, ua3, accA2)                             \
    GRP8(BUF, 3, ua0, ua1, ua2, ua3, accA3)                             \
    const v2f ub0 = {UB0.x, UB0.y}, ub1 = {UB0.z, UB0.w};               \
    const v2f ub2 = {UB1.x, UB1.y}, ub3 = {UB1.z, UB1.w};               \
    GRP8(BUF, 0, ub0, ub1, ub2, ub3, accB0)                             \
    GRP8(BUF, 1, ub0, ub1, ub2, ub3, accB1)                             \
    GRP8(BUF, 2, ub0, ub1, ub2, ub3, accB2)                             \
    GRP8(BUF, 3, ub0, ub1, ub2, ub3, accB3) }

#define LDQ(P, Q) (*(const float4*)((P) + (size_t)(Q) * 8192))

    // prologue: dg=0 current (buf0 + c-regs)
    float4 cA0 = LDQ(U0, 0), cA1 = LDQ(U0, 1);
    float4 cB0 = LDQ(U1, 0), cB1 = LDQ(U1, 1);
    LOAD_UNI(0, 0)

    for (int dg = 0; dg < 62; dg += 2) {
        // prefetch dg+1 into buf1/n-regs
        const float4 nA0 = LDQ(U0, 2*dg + 2), nA1 = LDQ(U0, 2*dg + 3);
        const float4 nB0 = LDQ(U1, 2*dg + 2), nB1 = LDQ(U1, 2*dg + 3);
        LOAD_UNI(1, dg + 1)
        COMPUTE(0, cA0, cA1, cB0, cB1)
        // prefetch dg+2 into buf0/c-regs
        cA0 = LDQ(U0, 2*dg + 4); cA1 = LDQ(U0, 2*dg + 5);
        cB0 = LDQ(U1, 2*dg + 4); cB1 = LDQ(U1, 2*dg + 5);
        LOAD_UNI(0, dg + 2)
        COMPUTE(1, nA0, nA1, nB0, nB1)
    }
    // epilogue: dg=62 in buf0/c-regs; load dg=63
    {
        const float4 nA0 = LDQ(U0, 126), nA1 = LDQ(U0, 127);
        const float4 nB0 = LDQ(U1, 126), nB1 = LDQ(U1, 127);
        LOAD_UNI(1, 63)
        COMPUTE(0, cA0, cA1, cB0, cB1)
        COMPUTE(1, nA0, nA1, nB0, nB1)
    }
#undef LDQ
#undef COMPUTE
#undef GRP8
#undef LOAD_UNI
#undef LOAD_ROW

    float* __restrict__ O = out + (size_t)(b * T_ + t0) * S_ + s0;
    O[0 * S_]      = sumv - 2.0f * (accA0.x + accA0.y);
    O[0 * S_ + 64] = sumv - 2.0f * (accB0.x + accB0.y);
    O[1 * S_]      = sumv - 2.0f * (accA1.x + accA1.y);
    O[1 * S_ + 64] = sumv - 2.0f * (accB1.x + accB1.y);
    O[2 * S_]      = sumv - 2.0f * (accA2.x + accA2.y);
    O[2 * S_ + 64] = sumv - 2.0f * (accB2.x + accB2.y);
    O[3 * S_]      = sumv - 2.0f * (accA3.x + accA3.y);
    O[3 * S_ + 64] = sumv - 2.0f * (accB3.x + accB3.y);
}

extern "C" void kernel_launch(void* const* d_in, const int* in_sizes, int n_in,
                              void* d_out, int out_size, void* d_ws, size_t ws_size,
                              hipStream_t stream) {
    const float* h_t = (const float*)d_in[0];  // [4,512,512]
    const float* h_s = (const float*)d_in[1];  // [4,512,512]
    const float* Wq  = (const float*)d_in[2];  // [512,512]
    const float* bq  = (const float*)d_in[3];  // [512]
    const float* Wc  = (const float*)d_in[4];  // [512,512]
    const float* v   = (const float*)d_in[5];  // [512]
    float* out = (float*)d_out;                // [4,512,512]

    float* Ea  = (float*)d_ws;                 // exp2(c*(h_t Wq^T + bq)) [2048][512]
    float* Eu4 = Ea + (size_t)B_ * T_ * D_;    // exp2(c*(h_s Wc^T)), d-quad-major

    gemm_exp_kernel<<<dim3(32, 8, 2), 256, 0, stream>>>(h_t, h_s, Wq, bq, Wc, Ea, Eu4);
    score_kernel<<<dim3(1024, 1, 1), 128, 0, stream>>>(Ea, Eu4, v, out);
}